// Round 5
// baseline (308.168 us; speedup 1.0000x reference)
//
#include <hip/hip_runtime.h>

typedef __attribute__((ext_vector_type(8))) short short8;
typedef __attribute__((ext_vector_type(4))) float f32x4;
typedef __attribute__((ext_vector_type(16))) float f32x16;

#define T_TOK 16384
#define DM 512
#define NE 8
#define BM 64
#define ROWB 1040  // padded LDS row stride: 65*16B -> bank-slot rotates by 1/row

__device__ __forceinline__ ushort f2bf(float v) {
  unsigned u = __float_as_uint(v);
  return (ushort)((u + 0x7FFFu + ((u >> 16) & 1u)) >> 16);
}

// ---------------- gating: logits + softmax, one wave per token ----------------
__global__ void gates_kernel(const float* __restrict__ x, const float* __restrict__ Wg,
                             const float* __restrict__ bg, float* __restrict__ gates) {
  int wid = (int)((blockIdx.x * blockDim.x + threadIdx.x) >> 6);
  int lane = threadIdx.x & 63;
  if (wid >= T_TOK) return;
  const float* xt = x + (size_t)wid * DM;
  float a[NE];
#pragma unroll
  for (int e = 0; e < NE; ++e) a[e] = 0.f;
  for (int d = lane; d < DM; d += 64) {
    float xv = xt[d];
    const float* wr = Wg + d * NE;
#pragma unroll
    for (int e = 0; e < NE; ++e) a[e] += xv * wr[e];
  }
#pragma unroll
  for (int e = 0; e < NE; ++e) {
#pragma unroll
    for (int off = 32; off > 0; off >>= 1) a[e] += __shfl_xor(a[e], off, 64);
  }
  float m = -1e30f;
#pragma unroll
  for (int e = 0; e < NE; ++e) { a[e] += bg[e]; m = fmaxf(m, a[e]); }
  float s = 0.f;
#pragma unroll
  for (int e = 0; e < NE; ++e) { a[e] = __expf(a[e] - m); s += a[e]; }
  float inv = 1.f / s;
  if (lane < NE) gates[(size_t)wid * NE + lane] = a[lane] * inv;
}

// -------- weight reorder: W[e][k][n] fp32 -> 32x32x16 A-fragment-major bf16 ----
// chunkid = (e*32 + kh)*16 + ft ; lane l holds
// W[e][kh*16 + (l>>5)*8 + j][ft*32 + (l&31)]  for j=0..7 (bf16).
__global__ void reorder_w_kernel(const float* __restrict__ W, ushort* __restrict__ WF) {
  int c = blockIdx.x * blockDim.x + threadIdx.x;  // 262144 threads
  int l = c & 63;
  int chunk = c >> 6;
  int ft = chunk & 15;
  int kh = (chunk >> 4) & 31;
  int e = chunk >> 9;
  int n = ft * 32 + (l & 31);
  int k0 = kh * 16 + (l >> 5) * 8;
  const float* src = W + ((size_t)e * DM + k0) * DM + n;
  short8 v;
#pragma unroll
  for (int j = 0; j < 8; ++j) v[j] = (short)f2bf(src[(size_t)j * DM]);
  *reinterpret_cast<short8*>(WF + (size_t)c * 8) = v;
}

// ---------------- fused MoE main kernel ----------------
// 256 blocks x 512 threads (8 waves). Wave w owns output cols [w*64, w*64+64).
// 32x32x16 MFMA, swapped operands: D[f][t] = mfma(A=W-frag, B=act-frag).
// Cross-expert merged loop: GEMM2(e) and GEMM1(e+1) share one 16-kt loop
// (16 MFMA/kt, 8 independent chains) -> 2x MFMA work per barrier phase.
__global__ __launch_bounds__(512, 2) void moe_main_kernel(
    const float* __restrict__ x, const ushort* __restrict__ W1F,
    const float* __restrict__ b1, const ushort* __restrict__ W2F,
    const float* __restrict__ b2, const float* __restrict__ gates,
    float* __restrict__ out) {
  extern __shared__ char smem[];
  char* x_lds = smem;                        // 64 rows * 1040 B = 66560
  char* h_lds = smem + 66560;                // 66560
  float* g_lds = (float*)(smem + 133120);    // [64][9] f32

  const int tid = threadIdx.x;
  const int lane = tid & 63;
  const int w = tid >> 6;        // wave 0..7
  const int hi = lane >> 5;      // k-half
  const int l31 = lane & 31;
  const int m0 = blockIdx.x * BM;

  const unsigned abase = (unsigned)l31 * ROWB + (unsigned)hi * 16;
  const unsigned wbase = (unsigned)l31 * ROWB + (unsigned)(w * 128 + hi * 8);

#define BARRIER()                                        \
  do {                                                   \
    asm volatile("s_waitcnt lgkmcnt(0)" ::: "memory");   \
    __builtin_amdgcn_s_barrier();                        \
  } while (0)

#define LDACT(lds, kt, ks, ni) \
  (*reinterpret_cast<const short8*>((lds) + abase + (ni) * (32 * ROWB) + ((kt) * 64 + (ks) * 32)))

#define MF(d, a, b) d = __builtin_amdgcn_mfma_f32_32x32x16_bf16(a, b, d, 0, 0, 0)

  {  // gates -> LDS (padded stride 9)
    int t = tid >> 3, e = tid & 7;
    g_lds[t * 9 + e] = gates[(size_t)(m0 + t) * NE + e];
  }

  // stage x tile: fp32 -> bf16, padded rows
  for (int i = tid; i < BM * DM / 4; i += 512) {
    int t = i >> 7;
    int kd = (i & 127) * 4;
    float4 v = *reinterpret_cast<const float4*>(x + ((size_t)(m0 + t) << 9) + kd);
    unsigned lo = (unsigned)f2bf(v.x) | ((unsigned)f2bf(v.y) << 16);
    unsigned hb = (unsigned)f2bf(v.z) | ((unsigned)f2bf(v.w) << 16);
    *reinterpret_cast<uint2*>(x_lds + (unsigned)(t * ROWB + kd * 2)) = make_uint2(lo, hb);
  }

  const short8* wp1 = reinterpret_cast<const short8*>(W1F) + w * 128 + lane;
  const short8* wp2 = reinterpret_cast<const short8*>(W2F) + w * 128 + lane;

  f32x16 acc[2][2];
  f32x16 hacc[2][2];
#pragma unroll
  for (int mi = 0; mi < 2; ++mi)
#pragma unroll
    for (int ni = 0; ni < 2; ++ni)
#pragma unroll
      for (int i = 0; i < 16; ++i) { acc[mi][ni][i] = 0.f; hacc[mi][ni][i] = 0.f; }

  short8 wA[2][4];  // GEMM2 weight stream (-> acc)
  short8 wB[2][4];  // GEMM1 weight stream (-> hacc)

  // GEMM1(0) kt0 prologue (global loads, legal before barrier)
#pragma unroll
  for (int ks = 0; ks < 2; ++ks)
#pragma unroll
    for (int mi = 0; mi < 2; ++mi) wB[0][ks * 2 + mi] = wp1[ks * 1024 + mi * 64];

  BARRIER();  // x tile staged

  // ---------- standalone GEMM1(0): hacc = W1(0) . x ----------
#pragma unroll
  for (int kt = 0; kt < 16; ++kt) {
    if (kt < 15) {
#pragma unroll
      for (int ks = 0; ks < 2; ++ks)
#pragma unroll
        for (int mi = 0; mi < 2; ++mi)
          wB[(kt + 1) & 1][ks * 2 + mi] = wp1[(kt + 1) * 2048 + ks * 1024 + mi * 64];
    }
    short8 a1[4];
#pragma unroll
    for (int ks = 0; ks < 2; ++ks)
#pragma unroll
      for (int ni = 0; ni < 2; ++ni) a1[ks * 2 + ni] = LDACT(x_lds, kt, ks, ni);
    __builtin_amdgcn_s_setprio(1);
#pragma unroll
    for (int ks = 0; ks < 2; ++ks)
#pragma unroll
      for (int mi = 0; mi < 2; ++mi)
#pragma unroll
        for (int ni = 0; ni < 2; ++ni)
          MF(hacc[mi][ni], wB[kt & 1][ks * 2 + mi], a1[ks * 2 + ni]);
    __builtin_amdgcn_s_setprio(0);
  }

  for (int e = 0; e < NE; ++e) {
    const short8* we2 = wp2 + (size_t)e * 32768;
    const short8* wn1 = wp1 + (size_t)(e + 1) * 32768;

    BARRIER();  // all reads of h_lds from previous phase are done

    // next-phase weight kt0 prologues: stay in flight across epilogue
#pragma unroll
    for (int ks = 0; ks < 2; ++ks)
#pragma unroll
      for (int mi = 0; mi < 2; ++mi) wA[0][ks * 2 + mi] = we2[ks * 1024 + mi * 64];
    if (e < NE - 1) {
#pragma unroll
      for (int ks = 0; ks < 2; ++ks)
#pragma unroll
        for (int mi = 0; mi < 2; ++mi) wB[0][ks * 2 + mi] = wn1[ks * 1024 + mi * 64];
    }

    // epilogue: h(e)[t][f] = relu(hacc + b1[f]) * g[t] -> h_lds
#pragma unroll
    for (int ni = 0; ni < 2; ++ni) {
      int t = ni * 32 + l31;
      float g = g_lds[t * 9 + e];
#pragma unroll
      for (int mi = 0; mi < 2; ++mi) {
#pragma unroll
        for (int j = 0; j < 4; ++j) {
          float4 b1q = *reinterpret_cast<const float4*>(
              b1 + e * DM + w * 64 + mi * 32 + j * 8 + hi * 4);
          float v0 = fmaxf(hacc[mi][ni][j * 4 + 0] + b1q.x, 0.f) * g;
          float v1 = fmaxf(hacc[mi][ni][j * 4 + 1] + b1q.y, 0.f) * g;
          float v2 = fmaxf(hacc[mi][ni][j * 4 + 2] + b1q.z, 0.f) * g;
          float v3 = fmaxf(hacc[mi][ni][j * 4 + 3] + b1q.w, 0.f) * g;
          unsigned lo = (unsigned)f2bf(v0) | ((unsigned)f2bf(v1) << 16);
          unsigned hb = (unsigned)f2bf(v2) | ((unsigned)f2bf(v3) << 16);
          *reinterpret_cast<uint2*>(h_lds + wbase + ni * (32 * ROWB) + mi * 64 + j * 16) =
              make_uint2(lo, hb);
        }
      }
    }
    BARRIER();  // h(e) visible

    if (e < NE - 1) {
      // ---------- merged: acc += W2(e).h(e)  ||  hacc = W1(e+1).x ----------
#pragma unroll
      for (int mi = 0; mi < 2; ++mi)
#pragma unroll
        for (int ni = 0; ni < 2; ++ni)
#pragma unroll
          for (int i = 0; i < 16; ++i) hacc[mi][ni][i] = 0.f;

#pragma unroll
      for (int kt = 0; kt < 16; ++kt) {
        if (kt < 15) {
#pragma unroll
          for (int ks = 0; ks < 2; ++ks)
#pragma unroll
            for (int mi = 0; mi < 2; ++mi) {
              wA[(kt + 1) & 1][ks * 2 + mi] = we2[(kt + 1) * 2048 + ks * 1024 + mi * 64];
              wB[(kt + 1) & 1][ks * 2 + mi] = wn1[(kt + 1) * 2048 + ks * 1024 + mi * 64];
            }
        }
        short8 a2[4], a1[4];
#pragma unroll
        for (int ks = 0; ks < 2; ++ks)
#pragma unroll
          for (int ni = 0; ni < 2; ++ni) {
            a2[ks * 2 + ni] = LDACT(h_lds, kt, ks, ni);
            a1[ks * 2 + ni] = LDACT(x_lds, kt, ks, ni);
          }
        __builtin_amdgcn_s_setprio(1);
#pragma unroll
        for (int ks = 0; ks < 2; ++ks)
#pragma unroll
          for (int mi = 0; mi < 2; ++mi)
#pragma unroll
            for (int ni = 0; ni < 2; ++ni) {
              MF(acc[mi][ni], wA[kt & 1][ks * 2 + mi], a2[ks * 2 + ni]);
              MF(hacc[mi][ni], wB[kt & 1][ks * 2 + mi], a1[ks * 2 + ni]);
            }
        __builtin_amdgcn_s_setprio(0);
      }
    } else {
      // ---------- standalone GEMM2(7): acc += W2(7).h(7) ----------
#pragma unroll
      for (int kt = 0; kt < 16; ++kt) {
        if (kt < 15) {
#pragma unroll
          for (int ks = 0; ks < 2; ++ks)
#pragma unroll
            for (int mi = 0; mi < 2; ++mi)
              wA[(kt + 1) & 1][ks * 2 + mi] = we2[(kt + 1) * 2048 + ks * 1024 + mi * 64];
        }
        short8 a2[4];
#pragma unroll
        for (int ks = 0; ks < 2; ++ks)
#pragma unroll
          for (int ni = 0; ni < 2; ++ni) a2[ks * 2 + ni] = LDACT(h_lds, kt, ks, ni);
        __builtin_amdgcn_s_setprio(1);
#pragma unroll
        for (int ks = 0; ks < 2; ++ks)
#pragma unroll
          for (int mi = 0; mi < 2; ++mi)
#pragma unroll
            for (int ni = 0; ni < 2; ++ni)
              MF(acc[mi][ni], wA[kt & 1][ks * 2 + mi], a2[ks * 2 + ni]);
        __builtin_amdgcn_s_setprio(0);
      }
    }
  }

  // fold Sum_e gate[t][e] * b2[e][d] once
#pragma unroll
  for (int e = 0; e < NE; ++e) {
    float ge0 = g_lds[l31 * 9 + e];
    float ge1 = g_lds[(32 + l31) * 9 + e];
#pragma unroll
    for (int mi = 0; mi < 2; ++mi)
#pragma unroll
      for (int j = 0; j < 4; ++j) {
        float4 b2q = *reinterpret_cast<const float4*>(
            b2 + e * DM + w * 64 + mi * 32 + j * 8 + hi * 4);
        acc[mi][0][j * 4 + 0] += ge0 * b2q.x;
        acc[mi][0][j * 4 + 1] += ge0 * b2q.y;
        acc[mi][0][j * 4 + 2] += ge0 * b2q.z;
        acc[mi][0][j * 4 + 3] += ge0 * b2q.w;
        acc[mi][1][j * 4 + 0] += ge1 * b2q.x;
        acc[mi][1][j * 4 + 1] += ge1 * b2q.y;
        acc[mi][1][j * 4 + 2] += ge1 * b2q.z;
        acc[mi][1][j * 4 + 3] += ge1 * b2q.w;
      }
  }

  // write out: per (mi,ni,j) a float4 of consecutive d
#pragma unroll
  for (int ni = 0; ni < 2; ++ni) {
    int t = m0 + ni * 32 + l31;
#pragma unroll
    for (int mi = 0; mi < 2; ++mi)
#pragma unroll
      for (int j = 0; j < 4; ++j) {
        f32x4 v;
        v[0] = acc[mi][ni][j * 4 + 0];
        v[1] = acc[mi][ni][j * 4 + 1];
        v[2] = acc[mi][ni][j * 4 + 2];
        v[3] = acc[mi][ni][j * 4 + 3];
        *reinterpret_cast<f32x4*>(out + (size_t)t * DM + w * 64 + mi * 32 + j * 8 + hi * 4) = v;
      }
  }
#undef LDACT
#undef MF
#undef BARRIER
}

extern "C" void kernel_launch(void* const* d_in, const int* in_sizes, int n_in,
                              void* d_out, int out_size, void* d_ws, size_t ws_size,
                              hipStream_t stream) {
  const float* x  = (const float*)d_in[0];
  const float* W1 = (const float*)d_in[1];
  const float* b1 = (const float*)d_in[2];
  const float* W2 = (const float*)d_in[3];
  const float* b2 = (const float*)d_in[4];
  const float* Wg = (const float*)d_in[5];
  const float* bg = (const float*)d_in[6];
  float* out = (float*)d_out;

  float* gates = (float*)d_ws;                              // 524288 B
  ushort* W1F = (ushort*)((char*)d_ws + 524288);            // 4 MiB
  ushort* W2F = (ushort*)((char*)d_ws + 524288 + 4194304);  // 4 MiB

  hipFuncSetAttribute((const void*)moe_main_kernel,
                      hipFuncAttributeMaxDynamicSharedMemorySize, 135424);

  gates_kernel<<<T_TOK / 4, 256, 0, stream>>>(x, Wg, bg, gates);
  reorder_w_kernel<<<1024, 256, 0, stream>>>(W1, W1F);
  reorder_w_kernel<<<1024, 256, 0, stream>>>(W2, W2F);
  moe_main_kernel<<<T_TOK / BM, 512, 135424, stream>>>(x, W1F, b1, W2F, b2, gates, out);
}

// Round 6
// 264.360 us; speedup vs baseline: 1.1657x; 1.1657x over previous
//
#include <hip/hip_runtime.h>

typedef __attribute__((ext_vector_type(8))) short short8;
typedef __attribute__((ext_vector_type(4))) float f32x4;
typedef __attribute__((ext_vector_type(16))) float f32x16;

#define T_TOK 16384
#define DM 512
#define NE 8
#define BM 64
#define ROWB 1040  // padded LDS row stride: 65*16B -> bank-slot rotates by 1/row

__device__ __forceinline__ ushort f2bf(float v) {
  unsigned u = __float_as_uint(v);
  return (ushort)((u + 0x7FFFu + ((u >> 16) & 1u)) >> 16);
}

// ---------------- gating: logits + softmax, one wave per token ----------------
__global__ void gates_kernel(const float* __restrict__ x, const float* __restrict__ Wg,
                             const float* __restrict__ bg, float* __restrict__ gates) {
  int wid = (int)((blockIdx.x * blockDim.x + threadIdx.x) >> 6);
  int lane = threadIdx.x & 63;
  if (wid >= T_TOK) return;
  const float* xt = x + (size_t)wid * DM;
  float a[NE];
#pragma unroll
  for (int e = 0; e < NE; ++e) a[e] = 0.f;
  for (int d = lane; d < DM; d += 64) {
    float xv = xt[d];
    const float* wr = Wg + d * NE;
#pragma unroll
    for (int e = 0; e < NE; ++e) a[e] += xv * wr[e];
  }
#pragma unroll
  for (int e = 0; e < NE; ++e) {
#pragma unroll
    for (int off = 32; off > 0; off >>= 1) a[e] += __shfl_xor(a[e], off, 64);
  }
  float m = -1e30f;
#pragma unroll
  for (int e = 0; e < NE; ++e) { a[e] += bg[e]; m = fmaxf(m, a[e]); }
  float s = 0.f;
#pragma unroll
  for (int e = 0; e < NE; ++e) { a[e] = __expf(a[e] - m); s += a[e]; }
  float inv = 1.f / s;
  if (lane < NE) gates[(size_t)wid * NE + lane] = a[lane] * inv;
}

// -------- weight reorder: W[e][k][n] fp32 -> 32x32x16 A-fragment-major bf16 ----
// chunkid = (e*32 + kh)*16 + ft ; lane l holds
// W[e][kh*16 + (l>>5)*8 + j][ft*32 + (l&31)]  for j=0..7 (bf16).
__global__ void reorder_w_kernel(const float* __restrict__ W, ushort* __restrict__ WF) {
  int c = blockIdx.x * blockDim.x + threadIdx.x;  // 262144 threads
  int l = c & 63;
  int chunk = c >> 6;
  int ft = chunk & 15;
  int kh = (chunk >> 4) & 31;
  int e = chunk >> 9;
  int n = ft * 32 + (l & 31);
  int k0 = kh * 16 + (l >> 5) * 8;
  const float* src = W + ((size_t)e * DM + k0) * DM + n;
  short8 v;
#pragma unroll
  for (int j = 0; j < 8; ++j) v[j] = (short)f2bf(src[(size_t)j * DM]);
  *reinterpret_cast<short8*>(WF + (size_t)c * 8) = v;
}

// ---------------- fused MoE main kernel ----------------
// 256 blocks x 512 threads (8 waves). Wave w owns output cols [w*64, w*64+64).
// 32x32x16 MFMA, swapped operands: D[f][t] = mfma(A=W-frag, B=act-frag).
// Merged loop: GEMM2(e) || GEMM1(e+1) in one 16-kt loop (16 MFMA/kt, 8 chains),
// register-budgeted: wA 1-ahead double-buffer, wB JIT, acts JIT (~230 VGPR).
__global__ __launch_bounds__(512, 2) void moe_main_kernel(
    const float* __restrict__ x, const ushort* __restrict__ W1F,
    const float* __restrict__ b1, const ushort* __restrict__ W2F,
    const float* __restrict__ b2, const float* __restrict__ gates,
    float* __restrict__ out) {
  extern __shared__ char smem[];
  char* x_lds = smem;                        // 64 rows * 1040 B = 66560
  char* h_lds = smem + 66560;                // 66560
  float* g_lds = (float*)(smem + 133120);    // [64][9] f32

  const int tid = threadIdx.x;
  const int lane = tid & 63;
  const int w = tid >> 6;        // wave 0..7
  const int hi = lane >> 5;      // k-half
  const int l31 = lane & 31;
  const int m0 = blockIdx.x * BM;

  const unsigned abase = (unsigned)l31 * ROWB + (unsigned)hi * 16;
  const unsigned wbase = (unsigned)l31 * ROWB + (unsigned)(w * 128 + hi * 8);

#define BARRIER()                                        \
  do {                                                   \
    asm volatile("s_waitcnt lgkmcnt(0)" ::: "memory");   \
    __builtin_amdgcn_s_barrier();                        \
  } while (0)

#define LDACT(lds, kt, ks, ni) \
  (*reinterpret_cast<const short8*>((lds) + abase + (ni) * (32 * ROWB) + ((kt) * 64 + (ks) * 32)))

#define MF(d, a, b) d = __builtin_amdgcn_mfma_f32_32x32x16_bf16(a, b, d, 0, 0, 0)

  {  // gates -> LDS (padded stride 9)
    int t = tid >> 3, e = tid & 7;
    g_lds[t * 9 + e] = gates[(size_t)(m0 + t) * NE + e];
  }

  // stage x tile: fp32 -> bf16, padded rows
  for (int i = tid; i < BM * DM / 4; i += 512) {
    int t = i >> 7;
    int kd = (i & 127) * 4;
    float4 v = *reinterpret_cast<const float4*>(x + ((size_t)(m0 + t) << 9) + kd);
    unsigned lo = (unsigned)f2bf(v.x) | ((unsigned)f2bf(v.y) << 16);
    unsigned hb = (unsigned)f2bf(v.z) | ((unsigned)f2bf(v.w) << 16);
    *reinterpret_cast<uint2*>(x_lds + (unsigned)(t * ROWB + kd * 2)) = make_uint2(lo, hb);
  }

  const short8* wp1 = reinterpret_cast<const short8*>(W1F) + w * 128 + lane;
  const short8* wp2 = reinterpret_cast<const short8*>(W2F) + w * 128 + lane;

  f32x16 acc[2][2];
  f32x16 hacc[2][2];
#pragma unroll
  for (int mi = 0; mi < 2; ++mi)
#pragma unroll
    for (int ni = 0; ni < 2; ++ni)
#pragma unroll
      for (int i = 0; i < 16; ++i) { acc[mi][ni][i] = 0.f; hacc[mi][ni][i] = 0.f; }

  short8 wA[2][4];  // 1-ahead double-buffered weight stream

  // GEMM1(0) kt0 prologue (global loads, legal before barrier)
#pragma unroll
  for (int ks = 0; ks < 2; ++ks)
#pragma unroll
    for (int mi = 0; mi < 2; ++mi) wA[0][ks * 2 + mi] = wp1[ks * 1024 + mi * 64];

  BARRIER();  // x tile staged

  // ---------- standalone GEMM1(0): hacc = W1(0) . x ----------
#pragma unroll
  for (int kt = 0; kt < 16; ++kt) {
    if (kt < 15) {
#pragma unroll
      for (int ks = 0; ks < 2; ++ks)
#pragma unroll
        for (int mi = 0; mi < 2; ++mi)
          wA[(kt + 1) & 1][ks * 2 + mi] = wp1[(kt + 1) * 2048 + ks * 1024 + mi * 64];
    }
    short8 a1[4];
#pragma unroll
    for (int ks = 0; ks < 2; ++ks)
#pragma unroll
      for (int ni = 0; ni < 2; ++ni) a1[ks * 2 + ni] = LDACT(x_lds, kt, ks, ni);
    __builtin_amdgcn_s_setprio(1);
#pragma unroll
    for (int ks = 0; ks < 2; ++ks)
#pragma unroll
      for (int mi = 0; mi < 2; ++mi)
#pragma unroll
        for (int ni = 0; ni < 2; ++ni)
          MF(hacc[mi][ni], wA[kt & 1][ks * 2 + mi], a1[ks * 2 + ni]);
    __builtin_amdgcn_s_setprio(0);
  }

  for (int e = 0; e < NE; ++e) {
    const short8* we2 = wp2 + (size_t)e * 32768;
    const short8* wn1 = wp1 + (size_t)(e + 1) * 32768;

    BARRIER();  // h_lds reads from previous merged loop are done

    // W2(e) kt0 prologue: stays in flight across epilogue + barrier
#pragma unroll
    for (int ks = 0; ks < 2; ++ks)
#pragma unroll
      for (int mi = 0; mi < 2; ++mi) wA[0][ks * 2 + mi] = we2[ks * 1024 + mi * 64];

    // epilogue: h(e)[t][f] = relu(hacc + b1[f]) * g[t] -> h_lds
#pragma unroll
    for (int ni = 0; ni < 2; ++ni) {
      int t = ni * 32 + l31;
      float g = g_lds[t * 9 + e];
#pragma unroll
      for (int mi = 0; mi < 2; ++mi) {
#pragma unroll
        for (int j = 0; j < 4; ++j) {
          float4 b1q = *reinterpret_cast<const float4*>(
              b1 + e * DM + w * 64 + mi * 32 + j * 8 + hi * 4);
          float v0 = fmaxf(hacc[mi][ni][j * 4 + 0] + b1q.x, 0.f) * g;
          float v1 = fmaxf(hacc[mi][ni][j * 4 + 1] + b1q.y, 0.f) * g;
          float v2 = fmaxf(hacc[mi][ni][j * 4 + 2] + b1q.z, 0.f) * g;
          float v3 = fmaxf(hacc[mi][ni][j * 4 + 3] + b1q.w, 0.f) * g;
          unsigned lo = (unsigned)f2bf(v0) | ((unsigned)f2bf(v1) << 16);
          unsigned hb = (unsigned)f2bf(v2) | ((unsigned)f2bf(v3) << 16);
          *reinterpret_cast<uint2*>(h_lds + wbase + ni * (32 * ROWB) + mi * 64 + j * 16) =
              make_uint2(lo, hb);
        }
      }
    }
    BARRIER();  // h(e) visible

    if (e < NE - 1) {
      // ---------- merged: acc += W2(e).h(e)  ||  hacc = W1(e+1).x ----------
#pragma unroll
      for (int mi = 0; mi < 2; ++mi)
#pragma unroll
        for (int ni = 0; ni < 2; ++ni)
#pragma unroll
          for (int i = 0; i < 16; ++i) hacc[mi][ni][i] = 0.f;

#pragma unroll
      for (int kt = 0; kt < 16; ++kt) {
        // JIT wB for this kt (issued FIRST so its vmcnt-wait leaves wA[next] in flight)
        short8 wBj[4];
#pragma unroll
        for (int ks = 0; ks < 2; ++ks)
#pragma unroll
          for (int mi = 0; mi < 2; ++mi)
            wBj[ks * 2 + mi] = wn1[kt * 2048 + ks * 1024 + mi * 64];
        if (kt < 15) {
#pragma unroll
          for (int ks = 0; ks < 2; ++ks)
#pragma unroll
            for (int mi = 0; mi < 2; ++mi)
              wA[(kt + 1) & 1][ks * 2 + mi] = we2[(kt + 1) * 2048 + ks * 1024 + mi * 64];
        }
        short8 a2[4], a1[4];
#pragma unroll
        for (int ks = 0; ks < 2; ++ks)
#pragma unroll
          for (int ni = 0; ni < 2; ++ni) {
            a2[ks * 2 + ni] = LDACT(h_lds, kt, ks, ni);
            a1[ks * 2 + ni] = LDACT(x_lds, kt, ks, ni);
          }
        __builtin_amdgcn_s_setprio(1);
        // acc chain first: wA[cur] already resident, a2 via short lgkm wait;
        // these 8 MFMAs cover wBj's L2 latency.
#pragma unroll
        for (int ks = 0; ks < 2; ++ks)
#pragma unroll
          for (int mi = 0; mi < 2; ++mi)
#pragma unroll
            for (int ni = 0; ni < 2; ++ni)
              MF(acc[mi][ni], wA[kt & 1][ks * 2 + mi], a2[ks * 2 + ni]);
#pragma unroll
        for (int ks = 0; ks < 2; ++ks)
#pragma unroll
          for (int mi = 0; mi < 2; ++mi)
#pragma unroll
            for (int ni = 0; ni < 2; ++ni)
              MF(hacc[mi][ni], wBj[ks * 2 + mi], a1[ks * 2 + ni]);
        __builtin_amdgcn_s_setprio(0);
      }
    } else {
      // ---------- standalone GEMM2(7): acc += W2(7).h(7) ----------
#pragma unroll
      for (int kt = 0; kt < 16; ++kt) {
        if (kt < 15) {
#pragma unroll
          for (int ks = 0; ks < 2; ++ks)
#pragma unroll
            for (int mi = 0; mi < 2; ++mi)
              wA[(kt + 1) & 1][ks * 2 + mi] = we2[(kt + 1) * 2048 + ks * 1024 + mi * 64];
        }
        short8 a2[4];
#pragma unroll
        for (int ks = 0; ks < 2; ++ks)
#pragma unroll
          for (int ni = 0; ni < 2; ++ni) a2[ks * 2 + ni] = LDACT(h_lds, kt, ks, ni);
        __builtin_amdgcn_s_setprio(1);
#pragma unroll
        for (int ks = 0; ks < 2; ++ks)
#pragma unroll
          for (int mi = 0; mi < 2; ++mi)
#pragma unroll
            for (int ni = 0; ni < 2; ++ni)
              MF(acc[mi][ni], wA[kt & 1][ks * 2 + mi], a2[ks * 2 + ni]);
        __builtin_amdgcn_s_setprio(0);
      }
    }
  }

  // fold Sum_e gate[t][e] * b2[e][d] once
#pragma unroll
  for (int e = 0; e < NE; ++e) {
    float ge0 = g_lds[l31 * 9 + e];
    float ge1 = g_lds[(32 + l31) * 9 + e];
#pragma unroll
    for (int mi = 0; mi < 2; ++mi)
#pragma unroll
      for (int j = 0; j < 4; ++j) {
        float4 b2q = *reinterpret_cast<const float4*>(
            b2 + e * DM + w * 64 + mi * 32 + j * 8 + hi * 4);
        acc[mi][0][j * 4 + 0] += ge0 * b2q.x;
        acc[mi][0][j * 4 + 1] += ge0 * b2q.y;
        acc[mi][0][j * 4 + 2] += ge0 * b2q.z;
        acc[mi][0][j * 4 + 3] += ge0 * b2q.w;
        acc[mi][1][j * 4 + 0] += ge1 * b2q.x;
        acc[mi][1][j * 4 + 1] += ge1 * b2q.y;
        acc[mi][1][j * 4 + 2] += ge1 * b2q.z;
        acc[mi][1][j * 4 + 3] += ge1 * b2q.w;
      }
  }

  // write out: per (mi,ni,j) a float4 of consecutive d
#pragma unroll
  for (int ni = 0; ni < 2; ++ni) {
    int t = m0 + ni * 32 + l31;
#pragma unroll
    for (int mi = 0; mi < 2; ++mi)
#pragma unroll
      for (int j = 0; j < 4; ++j) {
        f32x4 v;
        v[0] = acc[mi][ni][j * 4 + 0];
        v[1] = acc[mi][ni][j * 4 + 1];
        v[2] = acc[mi][ni][j * 4 + 2];
        v[3] = acc[mi][ni][j * 4 + 3];
        *reinterpret_cast<f32x4*>(out + (size_t)t * DM + w * 64 + mi * 32 + j * 8 + hi * 4) = v;
      }
  }
#undef LDACT
#undef MF
#undef BARRIER
}

extern "C" void kernel_launch(void* const* d_in, const int* in_sizes, int n_in,
                              void* d_out, int out_size, void* d_ws, size_t ws_size,
                              hipStream_t stream) {
  const float* x  = (const float*)d_in[0];
  const float* W1 = (const float*)d_in[1];
  const float* b1 = (const float*)d_in[2];
  const float* W2 = (const float*)d_in[3];
  const float* b2 = (const float*)d_in[4];
  const float* Wg = (const float*)d_in[5];
  const float* bg = (const float*)d_in[6];
  float* out = (float*)d_out;

  float* gates = (float*)d_ws;                              // 524288 B
  ushort* W1F = (ushort*)((char*)d_ws + 524288);            // 4 MiB
  ushort* W2F = (ushort*)((char*)d_ws + 524288 + 4194304);  // 4 MiB

  hipFuncSetAttribute((const void*)moe_main_kernel,
                      hipFuncAttributeMaxDynamicSharedMemorySize, 135424);

  gates_kernel<<<T_TOK / 4, 256, 0, stream>>>(x, Wg, bg, gates);
  reorder_w_kernel<<<1024, 256, 0, stream>>>(W1, W1F);
  reorder_w_kernel<<<1024, 256, 0, stream>>>(W2, W2F);
  moe_main_kernel<<<T_TOK / BM, 512, 135424, stream>>>(x, W1F, b1, W2F, b2, gates, out);
}